// Round 1
// baseline (1662.303 us; speedup 1.0000x reference)
//
#include <hip/hip_runtime.h>
#include <stdint.h>

#define Hdim 4096
#define Bdim 4096
#define BHn  (Bdim * (long)Hdim)

typedef __attribute__((ext_vector_type(8))) short bf16x8;
typedef __attribute__((ext_vector_type(4))) short short4v;
typedef __attribute__((ext_vector_type(4))) float f32x4;

// fp32 -> bf16 (round-to-nearest-even), header-version independent
__device__ inline short f2bf(float f) {
    uint32_t u = __builtin_bit_cast(uint32_t, f);
    u += 0x7fffu + ((u >> 16) & 1u);
    return (short)(u >> 16);
}

// ---------- W [K,N] fp32 row-major -> Wt [N,K] bf16 row-major ----------
__global__ __launch_bounds__(256) void transpose_convert(
    const float* __restrict__ W, short* __restrict__ Wt) {
    __shared__ float tile[32][33];
    const int tx = threadIdx.x, ty = threadIdx.y;
    const int n0 = blockIdx.x * 32, k0 = blockIdx.y * 32;
#pragma unroll
    for (int j = 0; j < 32; j += 8)
        tile[ty + j][tx] = W[(long)(k0 + ty + j) * Hdim + n0 + tx];
    __syncthreads();
#pragma unroll
    for (int j = 0; j < 32; j += 8)
        Wt[(long)(n0 + ty + j) * Hdim + k0 + tx] = f2bf(tile[tx][ty + j]);
}

// ---------- token-shift mix: xk/xv/xr (bf16) + x copy ----------
__global__ __launch_bounds__(256) void mix_kernel(
    const float* __restrict__ x, const float* __restrict__ sx,
    const float* __restrict__ km, const float* __restrict__ vm, const float* __restrict__ rm,
    short* __restrict__ xk, short* __restrict__ xv, short* __restrict__ xr,
    float* __restrict__ xcopy) {
    const long i = ((long)blockIdx.x * blockDim.x + threadIdx.x) * 4;
    const int h = (int)(i & (Hdim - 1));
    float4 x4 = *(const float4*)(x + i);
    float4 s4 = *(const float4*)(sx + i);
    float4 k4 = *(const float4*)(km + h);
    float4 v4 = *(const float4*)(vm + h);
    float4 r4 = *(const float4*)(rm + h);
    *(float4*)(xcopy + i) = x4;
    const float* xp = (const float*)&x4;
    const float* sp = (const float*)&s4;
    const float* kp = (const float*)&k4;
    const float* vp = (const float*)&v4;
    const float* rp = (const float*)&r4;
    short4v ok, ov, orr;
#pragma unroll
    for (int e = 0; e < 4; ++e) {
        float d = xp[e] - sp[e];
        ok[e]  = f2bf(fmaf(kp[e], d, sp[e]));
        ov[e]  = f2bf(fmaf(vp[e], d, sp[e]));
        orr[e] = f2bf(fmaf(rp[e], d, sp[e]));
    }
    *(short4v*)(xk + i) = ok;
    *(short4v*)(xv + i) = ov;
    *(short4v*)(xr + i) = orr;
}

// ---------- WKV elementwise (in-place over k/v/rpre -> aa/bb/p2) ----------
__global__ __launch_bounds__(256) void wkv_kernel(
    float* __restrict__ kbuf,   // in: k,    out: aa
    float* __restrict__ vbuf,   // in: v,    out: bb
    float* __restrict__ rbuf,   // in: rpre, out: p2
    const float* __restrict__ sa, const float* __restrict__ sb, const float* __restrict__ spv,
    const float* __restrict__ td, const float* __restrict__ tf,
    short* __restrict__ rwkv) {
    const long i = ((long)blockIdx.x * blockDim.x + threadIdx.x) * 4;
    const int h = (int)(i & (Hdim - 1));
    float4 k4 = *(const float4*)(kbuf + i);
    float4 v4 = *(const float4*)(vbuf + i);
    float4 r4 = *(const float4*)(rbuf + i);
    float4 a4 = *(const float4*)(sa + i);
    float4 b4 = *(const float4*)(sb + i);
    float4 p4 = *(const float4*)(spv + i);
    float4 t4 = *(const float4*)(td + h);
    float4 f4 = *(const float4*)(tf + h);
    const float* kp = (const float*)&k4; const float* vp = (const float*)&v4;
    const float* rp = (const float*)&r4; const float* ap = (const float*)&a4;
    const float* bp = (const float*)&b4; const float* pp = (const float*)&p4;
    const float* tp = (const float*)&t4; const float* fp = (const float*)&f4;
    float4 aa4, bb4, p24; short4v rw;
    float* aao = (float*)&aa4; float* bbo = (float*)&bb4; float* p2o = (float*)&p24;
#pragma unroll
    for (int e = 0; e < 4; ++e) {
        float k = kp[e], v = vp[e], A = ap[e], Bb = bp[e], P = pp[e];
        float r = 1.f / (1.f + __expf(-rp[e]));
        float w = k + fp[e];
        float p = fmaxf(P, w);
        float e1 = __expf(P - p), e2 = __expf(w - p);
        float wkv = (e1 * A + e2 * v) / (e1 * Bb + e2);
        float w2 = P + tp[e];
        float pq = fmaxf(w2, k);
        float E1 = __expf(w2 - pq), E2 = __expf(k - pq);
        aao[e] = E1 * A + E2 * v;
        bbo[e] = E1 * Bb + E2;
        p2o[e] = pq;
        rw[e] = f2bf(r * wkv);
    }
    *(float4*)(kbuf + i) = aa4;
    *(float4*)(vbuf + i) = bb4;
    *(float4*)(rbuf + i) = p24;
    *(short4v*)(rwkv + i) = rw;
}

// ---------- GEMM: C[M,N] fp32 = A[M,K] bf16 @ Bt[N,K]^T bf16 ----------
#define BM 128
#define BN 128
#define BK 32

__global__ __launch_bounds__(256) void gemm_bt(
    const short* __restrict__ A, const short* __restrict__ Bt,
    float* __restrict__ C, int M, int N, int K) {
    __shared__ __align__(16) short As[BM * BK];
    __shared__ __align__(16) short Bs[BN * BK];

    const int tid  = threadIdx.x;
    const int wid  = tid >> 6;
    const int lane = tid & 63;
    const int m_blk = blockIdx.y * BM;
    const int n_blk = blockIdx.x * BN;
    const int wm = (wid >> 1) * 64;
    const int wn = (wid & 1) * 64;

    // staging: per global_load_lds call, wave covers 16 rows (4 lanes/row x 16B)
    const int srow = wid * 16 + (lane >> 2);
    const int scol = (lane & 3) * 8;              // element offset (8 bf16 = 16B)

    const short* Ag = A  + (long)(m_blk + srow) * K + scol;
    const short* Bg = Bt + (long)(n_blk + srow) * K + scol;
    short* AsBase = &As[wid * 16 * BK];           // wave-uniform LDS base
    short* BsBase = &Bs[wid * 16 * BK];

    f32x4 acc[4][4] = {};

    const int arow = lane & 15;
    const int koff = (lane >> 4) * 8;

    for (int k0 = 0; k0 < K; k0 += BK) {
        __builtin_amdgcn_global_load_lds(
            (const __attribute__((address_space(1))) void*)Ag,
            (__attribute__((address_space(3))) void*)AsBase, 16, 0, 0);
        __builtin_amdgcn_global_load_lds(
            (const __attribute__((address_space(1))) void*)(Ag + 64L * K),
            (__attribute__((address_space(3))) void*)(AsBase + 64 * BK), 16, 0, 0);
        __builtin_amdgcn_global_load_lds(
            (const __attribute__((address_space(1))) void*)Bg,
            (__attribute__((address_space(3))) void*)BsBase, 16, 0, 0);
        __builtin_amdgcn_global_load_lds(
            (const __attribute__((address_space(1))) void*)(Bg + 64L * K),
            (__attribute__((address_space(3))) void*)(BsBase + 64 * BK), 16, 0, 0);
        Ag += BK; Bg += BK;
        __syncthreads();

        bf16x8 af[4], bfv[4];
#pragma unroll
        for (int i = 0; i < 4; ++i)
            af[i] = *(const bf16x8*)&As[(wm + i * 16 + arow) * BK + koff];
#pragma unroll
        for (int j = 0; j < 4; ++j)
            bfv[j] = *(const bf16x8*)&Bs[(wn + j * 16 + arow) * BK + koff];
#pragma unroll
        for (int i = 0; i < 4; ++i)
#pragma unroll
            for (int j = 0; j < 4; ++j)
                acc[i][j] = __builtin_amdgcn_mfma_f32_16x16x32_bf16(
                    af[i], bfv[j], acc[i][j], 0, 0, 0);
        __syncthreads();
    }

    // epilogue: C/D layout col=lane&15, row=(lane>>4)*4+reg
    const int crow0 = m_blk + wm + (lane >> 4) * 4;
    const int ccol  = n_blk + wn + (lane & 15);
#pragma unroll
    for (int i = 0; i < 4; ++i)
#pragma unroll
        for (int j = 0; j < 4; ++j) {
            float* cp = C + (long)(crow0 + i * 16) * N + ccol + j * 16;
#pragma unroll
            for (int r = 0; r < 4; ++r)
                cp[(long)r * N] = acc[i][j][r];
        }
}

extern "C" void kernel_launch(void* const* d_in, const int* in_sizes, int n_in,
                              void* d_out, int out_size, void* d_ws, size_t ws_size,
                              hipStream_t stream) {
    const float* x  = (const float*)d_in[0];
    const float* sx = (const float*)d_in[1];
    const float* sa = (const float*)d_in[2];
    const float* sb = (const float*)d_in[3];
    const float* sp = (const float*)d_in[4];
    const float* td = (const float*)d_in[5];
    const float* tf = (const float*)d_in[6];
    const float* km = (const float*)d_in[7];
    const float* vm = (const float*)d_in[8];
    const float* rm = (const float*)d_in[9];
    const float* Wk = (const float*)d_in[10];
    const float* Wv = (const float*)d_in[11];
    const float* Wr = (const float*)d_in[12];
    const float* Wo = (const float*)d_in[13];

    float* out   = (float*)d_out;          // slot 0: out
    float* xcopy = out + BHn;              // slot 1: x
    float* kbuf  = out + 2 * BHn;          // slot 2: k -> aa
    float* vbuf  = out + 3 * BHn;          // slot 3: v -> bb
    float* rbuf  = out + 4 * BHn;          // slot 4: rpre -> p2

    short* wsW  = (short*)d_ws;            // H*H bf16 weight buffer (reused 4x)
    short* xk   = wsW + (long)Hdim * Hdim;
    short* xv   = xk + BHn;
    short* xr   = xv + BHn;
    short* rwkv = xk;                      // xk dead after first GEMM

    dim3 tb(32, 8), tg(Hdim / 32, Hdim / 32);
    dim3 gg(Hdim / BN, Bdim / BM);
    const int ew_blocks = (int)(BHn / 1024);   // 4 elems/thread, 256 thr/block

    mix_kernel<<<ew_blocks, 256, 0, stream>>>(x, sx, km, vm, rm, xk, xv, xr, xcopy);

    transpose_convert<<<tg, tb, 0, stream>>>(Wk, wsW);
    gemm_bt<<<gg, 256, 0, stream>>>(xk, wsW, kbuf, Bdim, Hdim, Hdim);
    transpose_convert<<<tg, tb, 0, stream>>>(Wv, wsW);
    gemm_bt<<<gg, 256, 0, stream>>>(xv, wsW, vbuf, Bdim, Hdim, Hdim);
    transpose_convert<<<tg, tb, 0, stream>>>(Wr, wsW);
    gemm_bt<<<gg, 256, 0, stream>>>(xr, wsW, rbuf, Bdim, Hdim, Hdim);

    wkv_kernel<<<ew_blocks, 256, 0, stream>>>(kbuf, vbuf, rbuf, sa, sb, sp, td, tf, rwkv);

    transpose_convert<<<tg, tb, 0, stream>>>(Wo, wsW);
    gemm_bt<<<gg, 256, 0, stream>>>(rwkv, wsW, out, Bdim, Hdim, Hdim);
}